// Round 10
// baseline (173.161 us; speedup 1.0000x reference)
//
#include <hip/hip_runtime.h>

typedef float f32x2 __attribute__((ext_vector_type(2)));

constexpr int BLOCK  = 256;
constexpr int IPT    = 2;   // anchors per thread, packed as one f32x2 lane-pair
constexpr int PASSES = 4;   // DIAGNOSTIC: exact 4x work replication, bitwise-same result

// wave-uniform broadcast of lane `l`'s value: pure VALU, no memory, no waitcnt
__device__ __forceinline__ float bcastf(float v, int l) {
    return __int_as_float(__builtin_amdgcn_readlane(__float_as_int(v), l));
}
// zero-instruction compiler barrier: forces re-execution of dependent math each pass
__device__ __forceinline__ float opq(float x) { asm volatile("" : "+v"(x)); return x; }

__global__ __launch_bounds__(BLOCK, 8) void assign_cls_label_kernel(
    const float4* __restrict__ anchors4,  // (B,N) float4: y,x,h,w (or y1,x1,y2,x2)
    const float4* __restrict__ gt4,       // (B,A) float4: y1,x1,y2,x2
    const int* __restrict__ gt_counts,    // (B,1)
    const int* __restrict__ use_anchor_p, // scalar
    int* __restrict__ out,                // (B,N)
    int N, int A)
{
#pragma clang fp contract(off)
    const int tid   = threadIdx.x;
    const int lane  = tid & 63;
    const int b     = blockIdx.y;                         // one batch per block: full TLP
    const int n0r   = blockIdx.x * (BLOCK * IPT) + tid;   // lane-contiguous -> coalesced
    const int n1r   = n0r + BLOCK;
    const int n0    = (n0r < N) ? n0r : N - 1;            // tail clamp (stores guarded)
    const int n1    = (n1r < N) ? n1r : N - 1;
    const int glane = (lane < A) ? lane : A - 1;          // lane i holds gt box i

    const float4 ac0  = anchors4[(size_t)b * N + n0];
    const float4 ac1  = anchors4[(size_t)b * N + n1];
    float4       cb   = gt4[(size_t)b * A + glane];       // per-lane staged gt box
    const int    count      = gt_counts[b];               // uniform scalar load
    const int    use_anchor = use_anchor_p[0];

    const float c26 = 1.0f / 67108864.0f;  // fl(i/u)>=0.5 <=> i-(0.5-2^-26)u >= 0 (sign-exact)

    f32x2 Y1, X1, Y2, X2, AREA;
    if (use_anchor) {
        const f32x2 H  = {ac0.z, ac1.z};
        const f32x2 W  = {ac0.w, ac1.w};
        const f32x2 Yc = {ac0.x, ac1.x};
        const f32x2 Xc = {ac0.y, ac1.y};
        Y1 = Yc - H * 0.5f;    // h*0.5 exact; one rounded sub == ref's y - h/2
        Y2 = Y1 + H;
        X1 = Xc - W * 0.5f;
        X2 = X1 + W;
        AREA = H * W;
    } else {
        Y1 = f32x2{ac0.x, ac1.x}; X1 = f32x2{ac0.y, ac1.y};
        Y2 = f32x2{ac0.z, ac1.z}; X2 = f32x2{ac0.w, ac1.w};
        AREA = (Y2 - Y1) * (X2 - X1);
    }
    f32x2 ACC = {-1.0f, -1.0f};

    // per-lane gt area (ref op order); broadcast copies bits -> identical to ref's ga
    float cga = (cb.z - cb.x) * (cb.w - cb.y);

    auto comp = [&](float gy1, float gx1, float gy2, float gx2, float ga) {
        f32x2 yy1, yy2, xx1, xx2;
        yy1.x = __builtin_amdgcn_fmed3f(Y1.x, gy1, gy2);
        yy1.y = __builtin_amdgcn_fmed3f(Y1.y, gy1, gy2);
        yy2.x = __builtin_amdgcn_fmed3f(Y2.x, gy1, gy2);
        yy2.y = __builtin_amdgcn_fmed3f(Y2.y, gy1, gy2);
        xx1.x = __builtin_amdgcn_fmed3f(X1.x, gx1, gx2);
        xx1.y = __builtin_amdgcn_fmed3f(X1.y, gx1, gx2);
        xx2.x = __builtin_amdgcn_fmed3f(X2.x, gx1, gx2);
        xx2.y = __builtin_amdgcn_fmed3f(X2.y, gx1, gx2);
        const f32x2 dy    = yy2 - yy1;
        const f32x2 dx    = xx2 - xx1;
        const f32x2 inter = dy * dx;
        const f32x2 u     = (AREA + ga) - inter;          // ref assoc: (area+ga)-inter
        const f32x2 mh    = {-0.5f, -0.5f};
        const f32x2 cc    = {c26, c26};
        const f32x2 e = __builtin_elementwise_fma(u, mh, inter);  // Sterbenz-exact band
        const f32x2 r = __builtin_elementwise_fma(u, cc, e);      // sign-exact decision
        ACC = __builtin_elementwise_max(ACC, r);
    };

#pragma clang loop unroll(disable)
    for (int pass = 0; pass < PASSES; ++pass) {
        // barrier every pass input: passes cannot be CSE'd/DCE'd, zero emitted code
        Y1.x = opq(Y1.x);  Y1.y = opq(Y1.y);
        Y2.x = opq(Y2.x);  Y2.y = opq(Y2.y);
        X1.x = opq(X1.x);  X1.y = opq(X1.y);
        X2.x = opq(X2.x);  X2.y = opq(X2.y);
        AREA.x = opq(AREA.x);  AREA.y = opq(AREA.y);
        cb.x = opq(cb.x);  cb.y = opq(cb.y);
        cb.z = opq(cb.z);  cb.w = opq(cb.w);
        cga  = opq(cga);

        if (A <= 64) {
            // zero-memory inner loop: broadcast lane gi's staged box via v_readlane
            for (int gi = 0; gi < count; ++gi) {
                comp(bcastf(cb.x, gi), bcastf(cb.y, gi),
                     bcastf(cb.z, gi), bcastf(cb.w, gi), bcastf(cga, gi));
            }
        } else {
            const float4* __restrict__ grow = gt4 + (size_t)b * A;
            for (int gi = 0; gi < count; ++gi) {
                const float4 g = grow[gi];
                comp(g.x, g.y, g.z, g.w, (g.z - g.x) * (g.w - g.y));
            }
        }
    }

    int* orow = out + (size_t)b * N;
    if (n0r < N) orow[n0r] = (ACC.x >= 0.0f) ? 1 : 0;
    if (n1r < N) orow[n1r] = (ACC.y >= 0.0f) ? 1 : 0;
}

extern "C" void kernel_launch(void* const* d_in, const int* in_sizes, int n_in,
                              void* d_out, int out_size, void* d_ws, size_t ws_size,
                              hipStream_t stream) {
    const float4* anchors4   = (const float4*)d_in[0];
    const float4* gt4        = (const float4*)d_in[1];
    const int*    gt_counts  = (const int*)d_in[2];
    const int*    use_anchor = (const int*)d_in[3];
    int*          out        = (int*)d_out;

    const int B = in_sizes[2];              // gt_counts is (B,1)
    const int A = in_sizes[1] / (4 * B);    // gt_bboxess is (B,A,4)
    const int N = in_sizes[0] / (4 * B);    // anchorss   is (B,N,4)

    dim3 grid((N + BLOCK * IPT - 1) / (BLOCK * IPT), B);
    hipLaunchKernelGGL(assign_cls_label_kernel, grid, dim3(BLOCK), 0, stream,
                       anchors4, gt4, gt_counts, use_anchor, out, N, A);
}

// Round 11
// 119.403 us; speedup vs baseline: 1.4502x; 1.4502x over previous
//
#include <hip/hip_runtime.h>

typedef float f32x2 __attribute__((ext_vector_type(2)));

constexpr int BLOCK = 256;
constexpr int IPT   = 4;   // anchors per thread: 2 packed f32x2 groups (feed amortized 4x)

// wave-uniform broadcast of lane `l`'s value: pure VALU, no memory, no waitcnt
__device__ __forceinline__ float bcastf(float v, int l) {
    return __int_as_float(__builtin_amdgcn_readlane(__float_as_int(v), l));
}

__global__ __launch_bounds__(BLOCK, 8) void assign_cls_label_kernel(
    const float4* __restrict__ anchors4,  // (B,N) float4: y,x,h,w (or y1,x1,y2,x2)
    const float4* __restrict__ gt4,       // (B,A) float4: y1,x1,y2,x2
    const int* __restrict__ gt_counts,    // (B,1)
    const int* __restrict__ use_anchor_p, // scalar
    int* __restrict__ out,                // (B,N)
    int N, int A)
{
#pragma clang fp contract(off)
    const int tid   = threadIdx.x;
    const int lane  = tid & 63;
    const int b     = blockIdx.x;          // batch cycles FASTEST in dispatch order:
    const int tile  = blockIdx.y;          // each CU gets a balanced mix of counts
    const int base  = tile * (BLOCK * IPT) + tid;
    const int glane = (lane < A) ? lane : A - 1;   // lane i holds gt box i

    int n[IPT];
#pragma unroll
    for (int k = 0; k < IPT; ++k) {
        const int nr = base + k * BLOCK;
        n[k] = (nr < N) ? nr : N - 1;      // tail clamp (stores guarded below)
    }

    const float4* arow = anchors4 + (size_t)b * N;
    float4 av[IPT];
#pragma unroll
    for (int k = 0; k < IPT; ++k) av[k] = arow[n[k]];   // coalesced, issued together

    const float4 cb         = gt4[(size_t)b * A + glane];  // per-lane staged gt box
    const int    count      = gt_counts[b];                // uniform scalar load
    const int    use_anchor = use_anchor_p[0];

    const float c26 = 1.0f / 67108864.0f;  // fl(i/u)>=0.5 <=> i-(0.5-2^-26)u >= 0 (sign-exact)

    // two f32x2 groups; all indices compile-time via full unroll (rule #20)
    f32x2 Y1[2], X1[2], Y2[2], X2[2], AREA[2], ACC[2];
#pragma unroll
    for (int q = 0; q < 2; ++q) {
        const float4 g0 = av[2 * q], g1 = av[2 * q + 1];
        if (use_anchor) {
            const f32x2 H  = {g0.z, g1.z};
            const f32x2 W  = {g0.w, g1.w};
            const f32x2 Yc = {g0.x, g1.x};
            const f32x2 Xc = {g0.y, g1.y};
            Y1[q] = Yc - H * 0.5f;   // h*0.5 exact; one rounded sub == ref's y - h/2
            Y2[q] = Y1[q] + H;
            X1[q] = Xc - W * 0.5f;
            X2[q] = X1[q] + W;
            AREA[q] = H * W;
        } else {
            Y1[q] = f32x2{g0.x, g1.x}; X1[q] = f32x2{g0.y, g1.y};
            Y2[q] = f32x2{g0.z, g1.z}; X2[q] = f32x2{g0.w, g1.w};
            AREA[q] = (Y2[q] - Y1[q]) * (X2[q] - X1[q]);
        }
        ACC[q] = f32x2{-1.0f, -1.0f};
    }

    // per-lane gt area (ref op order); broadcast copies bits -> identical to ref's ga
    const float cga = (cb.z - cb.x) * (cb.w - cb.y);

    if (A <= 64) {
        // zero-memory inner loop: 5 readlane broadcasts feed 4 anchor computations
        for (int gi = 0; gi < count; ++gi) {
            const float gy1 = bcastf(cb.x, gi);
            const float gx1 = bcastf(cb.y, gi);
            const float gy2 = bcastf(cb.z, gi);
            const float gx2 = bcastf(cb.w, gi);
            const float ga  = bcastf(cga,  gi);
#pragma unroll
            for (int q = 0; q < 2; ++q) {
                f32x2 yy1, yy2, xx1, xx2;
                yy1.x = __builtin_amdgcn_fmed3f(Y1[q].x, gy1, gy2);
                yy1.y = __builtin_amdgcn_fmed3f(Y1[q].y, gy1, gy2);
                yy2.x = __builtin_amdgcn_fmed3f(Y2[q].x, gy1, gy2);
                yy2.y = __builtin_amdgcn_fmed3f(Y2[q].y, gy1, gy2);
                xx1.x = __builtin_amdgcn_fmed3f(X1[q].x, gx1, gx2);
                xx1.y = __builtin_amdgcn_fmed3f(X1[q].y, gx1, gx2);
                xx2.x = __builtin_amdgcn_fmed3f(X2[q].x, gx1, gx2);
                xx2.y = __builtin_amdgcn_fmed3f(X2[q].y, gx1, gx2);
                const f32x2 dy    = yy2 - yy1;
                const f32x2 dx    = xx2 - xx1;
                const f32x2 inter = dy * dx;
                const f32x2 u     = (AREA[q] + ga) - inter;   // ref assoc
                const f32x2 mh    = {-0.5f, -0.5f};
                const f32x2 cc    = {c26, c26};
                const f32x2 e = __builtin_elementwise_fma(u, mh, inter); // Sterbenz band
                const f32x2 r = __builtin_elementwise_fma(u, cc, e);     // sign-exact
                ACC[q] = __builtin_elementwise_max(ACC[q], r);
            }
        }
    } else {
        // generic fallback (unused at A=64): uniform direct loads
        const float4* __restrict__ grow = gt4 + (size_t)b * A;
        for (int gi = 0; gi < count; ++gi) {
            const float4 g = grow[gi];
            const float ga = (g.z - g.x) * (g.w - g.y);
#pragma unroll
            for (int q = 0; q < 2; ++q) {
                f32x2 yy1, yy2, xx1, xx2;
                yy1.x = __builtin_amdgcn_fmed3f(Y1[q].x, g.x, g.z);
                yy1.y = __builtin_amdgcn_fmed3f(Y1[q].y, g.x, g.z);
                yy2.x = __builtin_amdgcn_fmed3f(Y2[q].x, g.x, g.z);
                yy2.y = __builtin_amdgcn_fmed3f(Y2[q].y, g.x, g.z);
                xx1.x = __builtin_amdgcn_fmed3f(X1[q].x, g.y, g.w);
                xx1.y = __builtin_amdgcn_fmed3f(X1[q].y, g.y, g.w);
                xx2.x = __builtin_amdgcn_fmed3f(X2[q].x, g.y, g.w);
                xx2.y = __builtin_amdgcn_fmed3f(X2[q].y, g.y, g.w);
                const f32x2 dy    = yy2 - yy1;
                const f32x2 dx    = xx2 - xx1;
                const f32x2 inter = dy * dx;
                const f32x2 u     = (AREA[q] + ga) - inter;
                const f32x2 mh    = {-0.5f, -0.5f};
                const f32x2 cc    = {c26, c26};
                const f32x2 e = __builtin_elementwise_fma(u, mh, inter);
                const f32x2 r = __builtin_elementwise_fma(u, cc, e);
                ACC[q] = __builtin_elementwise_max(ACC[q], r);
            }
        }
    }

    int* orow = out + (size_t)b * N;
#pragma unroll
    for (int q = 0; q < 2; ++q) {
        const int na = base + (2 * q) * BLOCK;
        const int nb = base + (2 * q + 1) * BLOCK;
        if (na < N) orow[na] = (ACC[q].x >= 0.0f) ? 1 : 0;
        if (nb < N) orow[nb] = (ACC[q].y >= 0.0f) ? 1 : 0;
    }
}

extern "C" void kernel_launch(void* const* d_in, const int* in_sizes, int n_in,
                              void* d_out, int out_size, void* d_ws, size_t ws_size,
                              hipStream_t stream) {
    const float4* anchors4   = (const float4*)d_in[0];
    const float4* gt4        = (const float4*)d_in[1];
    const int*    gt_counts  = (const int*)d_in[2];
    const int*    use_anchor = (const int*)d_in[3];
    int*          out        = (int*)d_out;

    const int B = in_sizes[2];              // gt_counts is (B,1)
    const int A = in_sizes[1] / (4 * B);    // gt_bboxess is (B,A,4)
    const int N = in_sizes[0] / (4 * B);    // anchorss   is (B,N,4)

    // x = batch (fastest-cycling in dispatch) -> balanced count mix per CU
    dim3 grid(B, (N + BLOCK * IPT - 1) / (BLOCK * IPT));
    hipLaunchKernelGGL(assign_cls_label_kernel, grid, dim3(BLOCK), 0, stream,
                       anchors4, gt4, gt_counts, use_anchor, out, N, A);
}